// Round 1
// baseline (182.041 us; speedup 1.0000x reference)
//

#include <hip/hip_runtime.h>
#include <hip/hip_bf16.h>
#include <math.h>

// ArcFace forward: out = S * modified, where modified == logits except at
// (row, label): cos(arccos(t) + MARGIN) = t*cos(m) - sqrt(1-t^2)*sin(m).
//
// R4 post-mortem: split copy+fixup landed 180.8 us total; scale_copy itself
// is 61 us at 3.36 TB/s moved (204.8 MB) vs 6.29 TB/s copy ceiling (m13).
// Counter evidence: VGPR_Count=24 < 32 needed for v[8] -> compiler sank
// stores between loads (load/store pairs, ~3 loads in flight, not 8).
// nt-stores bypass L2/L3 write-back (plain-store fillBuffer hits 6.8 TB/s).
//
// R5: (1) sched_barrier(0) between load cluster and store cluster forces all
// 8 loads to issue before any store (true 8-deep MLP per thread);
// (2) plain stores instead of nontemporal so L2/L3 absorb the write stream.
// Predicted: VGPR ~40-48, scale_copy 61 -> ~35 us, total ~150-160 us.

#define ARC_S      64.0f
#define COS_M      0.8775825618903728f   // cos(0.5)
#define SIN_M      0.4794255386042030f   // sin(0.5)

typedef float floatx4 __attribute__((ext_vector_type(4)));

__global__ __launch_bounds__(256) void scale_copy_kernel(
    const floatx4* __restrict__ in,
    floatx4*       __restrict__ out)
{
    // Each block owns a contiguous chunk of 2048 float4s (32 KB).
    // 3125 blocks x 2048 float4 == 6,400,000 float4 == 256x100000 floats
    // exactly: no guards anywhere.
    const size_t base = (size_t)blockIdx.x * 2048u + threadIdx.x;

    floatx4 v[8];
    #pragma unroll
    for (int j = 0; j < 8; ++j)        // 8 independent loads, no guards
        v[j] = in[base + j * 256];

    // Nothing may cross: all 8 loads issue before the first store/waitcnt.
    __builtin_amdgcn_sched_barrier(0);

    #pragma unroll
    for (int j = 0; j < 8; ++j)        // plain stores: let L2/L3 write-back
        out[base + j * 256] = v[j] * ARC_S;
}

// Handles (1) the 256 target-element fixups, (2) any flat tail not covered
// by full 2048-float4 chunks (empty for 256x100000).
__global__ __launch_bounds__(256) void fixup_kernel(
    const float* __restrict__ logits,
    const int*   __restrict__ labels,
    float*       __restrict__ out,
    int B, int C, size_t tailStart, size_t total)
{
    const int t = threadIdx.x;

    // target fixup: one thread per row
    if (t < B) {
        const int lbl = labels[t];
        if (lbl >= 0 && lbl < C) {
            const size_t idx = (size_t)t * (size_t)C + (size_t)lbl;
            const float x = logits[idx];
            const float s = sqrtf(fmaxf(0.0f, 1.0f - x * x));
            out[idx] = ARC_S * (x * COS_M - s * SIN_M);
        }
    }

    // scalar tail (generic-shape safety; no-op when total % 8192 == 0)
    for (size_t i = tailStart + t; i < total; i += 256)
        out[i] = ARC_S * logits[i];
}

extern "C" void kernel_launch(void* const* d_in, const int* in_sizes, int n_in,
                              void* d_out, int out_size, void* d_ws, size_t ws_size,
                              hipStream_t stream) {
    const float* logits = (const float*)d_in[0];
    const int*   labels = (const int*)d_in[1];
    float*       out    = (float*)d_out;

    const int B = in_sizes[1];                 // 256
    const int C = in_sizes[0] / B;             // 100000
    const size_t total  = (size_t)B * (size_t)C;       // 25.6e6 floats
    const size_t total4 = total / 4;                   // 6.4e6 float4s
    const int    nChunks = (int)(total4 / 2048);       // 3125 full chunks
    const size_t tailStart = (size_t)nChunks * 2048u * 4u;  // == total here

    scale_copy_kernel<<<dim3(nChunks), dim3(256), 0, stream>>>(
        (const floatx4*)logits, (floatx4*)out);
    fixup_kernel<<<dim3(1), dim3(256), 0, stream>>>(
        logits, labels, out, B, C, tailStart, total);
}
